// Round 15
// baseline (359.248 us; speedup 1.0000x reference)
//
#include <hip/hip_runtime.h>
#include <hip/hip_bf16.h>

#define NN 50000
#define NE 800000
#define DD 256
#define KK 512    // concat K for fused GEMM
#define PAD 64    // padded CSR row stride (max deg ~45 at 8 sigma; P(>64) ~ 0)
#define CSTR 16   // counter stride in ints (64 B -> one cacheline per counter)

// prep roles: blocks 0..6249 alternate fill/conv (1:1); then conv rest; then wcT.
#define FB 3125
#define CB 12500
#define WB 1024
#define PREP_GRID (2 * FB + (CB - FB) + WB)   // 16649

typedef unsigned short u16;
typedef unsigned int   u32;
typedef unsigned char  u8;
typedef __attribute__((ext_vector_type(8))) __bf16 bf16x8;
typedef __attribute__((ext_vector_type(4))) float  f32x4;
typedef __attribute__((ext_vector_type(2))) float  f32x2;
typedef __attribute__((ext_vector_type(8))) u16    u16x8;
typedef __attribute__((ext_vector_type(4))) u16    u16x4;

#define GLOAD_LDS16(g, l) \
  __builtin_amdgcn_global_load_lds((const __attribute__((address_space(1))) void*)(g), \
                                   (__attribute__((address_space(3))) void*)(l), 16, 0, 0)

static __device__ __forceinline__ u16 f2bf(float f) {
  u32 u = __float_as_uint(f);
  u32 r = (u + 0x7FFFu + ((u >> 16) & 1u)) >> 16;
  return (u16)r;
}

// ---------------- fused prep: INTERLEAVED CSR fill + f32->{bf16,fp8} + WcT ------
__global__ void k_prep(const int* __restrict__ src, const int* __restrict__ tgt,
                       int* __restrict__ cnt, int* __restrict__ col,
                       const float* __restrict__ x, u16* __restrict__ x_bf,
                       u32* __restrict__ x_f8,
                       const float* __restrict__ W1l, const float* __restrict__ W1r,
                       const float* __restrict__ W2l, const float* __restrict__ W2r,
                       u16* __restrict__ Wc1T, u16* __restrict__ Wc2T) {
  const int b = blockIdx.x;
  int role, idx;
  if (b < 2 * FB) {
    role = b & 1;  idx = b >> 1;
  } else if (b < 2 * FB + (CB - FB)) {
    role = 1;      idx = FB + (b - 2 * FB);
  } else {
    role = 2;      idx = b - (2 * FB + (CB - FB));
  }

  if (role == 0) {
    int i = idx * 256 + threadIdx.x;
    int t = tgt[i];
    int p = atomicAdd(&cnt[t * CSTR], 1);
    if (p < PAD) col[t * PAD + p] = src[i];
  } else if (role == 1) {
    int i = idx * 256 + threadIdx.x;
    const float4 v = *reinterpret_cast<const float4*>(x + i * 4);
    u16x4 o; o.x = f2bf(v.x); o.y = f2bf(v.y); o.z = f2bf(v.z); o.w = f2bf(v.w);
    *reinterpret_cast<u16x4*>(x_bf + i * 4) = o;
    int pk = __builtin_amdgcn_cvt_pk_fp8_f32(v.x, v.y, 0, false);
    pk = __builtin_amdgcn_cvt_pk_fp8_f32(v.z, v.w, pk, true);
    x_f8[i] = (u32)pk;
  } else {
    int gid = idx * 256 + threadIdx.x;  // 262144 total
    int layer = gid >> 17;
    int idx2 = gid & 131071;
    int n = idx2 >> 9, k = idx2 & 511;
    const float* Wl = layer ? W2l : W1l;
    const float* Wr = layer ? W2r : W1r;
    u16* WcT = layer ? Wc2T : Wc1T;
    float v = (k < DD) ? Wl[k * DD + n] : Wr[(k - DD) * DD + n];
    int reg = k >> 6, ko = k & 63;
    int k2 = (reg << 6) + ((((ko >> 3) ^ (n & 7)) << 3)) + (ko & 7);
    WcT[n * KK + k2] = f2bf(v);
  }
}

// ---------------- fused layer: gather-aggregate + GEMM in ONE kernel ----------------
// out = mean_agg(feat8) @ Wl + A1 @ Wr + bias  (K=512 concat, Wc pre-swizzled)
// Block: 64 nodes x 256 cols, 4 waves. Phase G: each wave gathers 16 nodes'
// fp8 rows (1 coalesced 256 B load/edge, scalar col) -> mean -> bf16 -> LDS
// (chunk-XOR swizzled). K-loop: agg half reads in-LDS tile; x half staged via
// global_load_lds. Co-resident blocks at different phases overlap gather & MFMA.
#define BM 64
#define BN 256
#define BK 64

template <int LAYER>
__launch_bounds__(256, 2)
__global__ void k_layer(const u8* __restrict__ feat8, const int* __restrict__ cnt,
                        const int* __restrict__ col, const u16* __restrict__ A1,
                        const u16* __restrict__ WcT, const float* __restrict__ bias,
                        u16* __restrict__ outb, u8* __restrict__ outf8,
                        float* __restrict__ outf, int M) {
  __shared__ alignas(16) u16 lAg[64 * 256];  // 32 KB agg tile, 512 B/row, swizzled
  __shared__ alignas(16) u16 lAx[64 * 64];   // 8 KB x K-tile
  __shared__ alignas(16) u16 lB[256 * 64];   // 32 KB B K-tile
  const int tid = threadIdx.x;
  const int rowBase = blockIdx.x * BM;
  const int wave = tid >> 6, lane = tid & 63;
  const int wc = wave;        // wave's 64-col strip
  const int l8 = lane >> 3;   // staging row within 8-row group
  const int ch = lane & 7;    // 16 B chunk within 128 B row

  // ---- Phase G: gather-aggregate rows [wave*16, wave*16+16) ----
  const int fo = lane * 4;    // fp8 feat offset: lane covers feats [4l,4l+4)
  // LDS write target: row*512 + region(lane>>4)*128 + swizzled chunk
  const int wbyte = (lane >> 4) * 128 +
                    (((((lane & 15) >> 1) ^ 0) << 4) | ((lane & 1) << 3));
#pragma unroll 1
  for (int n = 0; n < 16; ++n) {
    const int row = wave * 16 + n;
    const int node = rowBase + row;
    int deg = (node < M) ? cnt[node * CSTR] : 0;
    if (deg > PAD) deg = PAD;
    const int base = node * PAD;
    f32x4 a = {0.f, 0.f, 0.f, 0.f};
    int e = 0;
    for (; e + 3 < deg; e += 4) {   // MLP=4
      int c0 = col[base + e],     c1 = col[base + e + 1];
      int c2 = col[base + e + 2], c3 = col[base + e + 3];
      u32 v0 = *reinterpret_cast<const u32*>(feat8 + (size_t)c0 * DD + fo);
      u32 v1 = *reinterpret_cast<const u32*>(feat8 + (size_t)c1 * DD + fo);
      u32 v2 = *reinterpret_cast<const u32*>(feat8 + (size_t)c2 * DD + fo);
      u32 v3 = *reinterpret_cast<const u32*>(feat8 + (size_t)c3 * DD + fo);
      f32x2 p;
      p = __builtin_amdgcn_cvt_pk_f32_fp8((int)v0, false); a.x += p.x; a.y += p.y;
      p = __builtin_amdgcn_cvt_pk_f32_fp8((int)v0, true);  a.z += p.x; a.w += p.y;
      p = __builtin_amdgcn_cvt_pk_f32_fp8((int)v1, false); a.x += p.x; a.y += p.y;
      p = __builtin_amdgcn_cvt_pk_f32_fp8((int)v1, true);  a.z += p.x; a.w += p.y;
      p = __builtin_amdgcn_cvt_pk_f32_fp8((int)v2, false); a.x += p.x; a.y += p.y;
      p = __builtin_amdgcn_cvt_pk_f32_fp8((int)v2, true);  a.z += p.x; a.w += p.y;
      p = __builtin_amdgcn_cvt_pk_f32_fp8((int)v3, false); a.x += p.x; a.y += p.y;
      p = __builtin_amdgcn_cvt_pk_f32_fp8((int)v3, true);  a.z += p.x; a.w += p.y;
    }
    for (; e < deg; ++e) {
      u32 v = *reinterpret_cast<const u32*>(feat8 + (size_t)col[base + e] * DD + fo);
      f32x2 p;
      p = __builtin_amdgcn_cvt_pk_f32_fp8((int)v, false); a.x += p.x; a.y += p.y;
      p = __builtin_amdgcn_cvt_pk_f32_fp8((int)v, true);  a.z += p.x; a.w += p.y;
    }
    const float scale = (deg > 0) ? 1.0f / (float)deg : 0.0f;
    u16x4 o;
    o.x = f2bf(a.x * scale); o.y = f2bf(a.y * scale);
    o.z = f2bf(a.z * scale); o.w = f2bf(a.w * scale);
    // apply row-swizzle: chunk bits (4..6) XOR (row&7)
    int byte = (wbyte & ~0x70) | ((wbyte & 0x70) ^ ((row & 7) << 4));
    *reinterpret_cast<u16x4*>((char*)lAg + row * 512 + byte) = o;
  }
  // barrier below (after first B stage) orders lAg writes before reads

  f32x4 acc[4][4] = {};

  for (int k0 = 0; k0 < KK; k0 += BK) {
    const bool isAgg = (k0 < DD);
    if (k0) __syncthreads();   // WAR on lB (and lAx)
    if (!isAgg) {
      // stage x K-tile: 64 rows x 128 B; wave stages rows [wave*16, wave*16+16)
      const int kk = k0 - DD;
#pragma unroll
      for (int j = 0; j < 2; ++j) {
        int row = wave * 16 + j * 8 + l8;
        int grow = rowBase + row;
        int gr = (grow < M) ? grow : 0;
        const u16* g = A1 + (size_t)gr * DD + kk + ((ch ^ (row & 7)) << 3);
        GLOAD_LDS16(g, &lAx[(wave * 16 + j * 8) * BK]);
      }
    }
    // stage B K-tile: 256 rows x 128 B, linear (WcT pre-swizzled)
#pragma unroll
    for (int j = 0; j < 8; ++j) {
      int row = wave * 64 + j * 8 + l8;
      const u16* g = WcT + (size_t)row * KK + k0 + (ch << 3);
      GLOAD_LDS16(g, &lB[(wave * 64 + j * 8) * BK]);
    }
    __syncthreads();  // drains vmcnt + lgkmcnt (lAg writes on first pass)

#pragma unroll
    for (int ks = 0; ks < 2; ++ks) {
      const int kbyte = ks * 64 + (lane >> 4) * 16;
      bf16x8 af[4], bfg[4];
#pragma unroll
      for (int m = 0; m < 4; ++m) {
        int row = m * 16 + (lane & 15);
        int sw = kbyte ^ ((row & 7) << 4);
        af[m] = isAgg
          ? *reinterpret_cast<const bf16x8*>((const char*)lAg + row * 512 + (k0 << 1) + sw)
          : *reinterpret_cast<const bf16x8*>((const char*)lAx + row * 128 + sw);
      }
#pragma unroll
      for (int n = 0; n < 4; ++n) {
        int row = wc * 64 + n * 16 + (lane & 15);
        bfg[n] = *reinterpret_cast<const bf16x8*>((const char*)lB + row * 128 + (kbyte ^ ((row & 7) << 4)));
      }
#pragma unroll
      for (int m = 0; m < 4; ++m)
#pragma unroll
        for (int n = 0; n < 4; ++n)
          acc[m][n] = __builtin_amdgcn_mfma_f32_16x16x32_bf16(af[m], bfg[n], acc[m][n], 0, 0, 0);
    }
  }

  // epilogue: D layout col = lane&15, row = (lane>>4)*4 + reg  [m89-verified]
  const int lrow = (lane >> 4) * 4;
  const int lcol = lane & 15;
#pragma unroll
  for (int n = 0; n < 4; ++n) {
    const int gcol = wc * 64 + n * 16 + lcol;
    const float bv = bias[gcol];
#pragma unroll
    for (int m = 0; m < 4; ++m) {
#pragma unroll
      for (int r = 0; r < 4; ++r) {
        const int grow = rowBase + m * 16 + lrow + r;
        if (grow < M) {
          float v = acc[m][n][r] + bv;
          if (LAYER == 1) {
            v = fmaxf(v, 0.0f);
            outb[grow * DD + gcol] = f2bf(v);
            int pk = __builtin_amdgcn_cvt_pk_fp8_f32(v, 0.0f, 0, false);
            outf8[grow * DD + gcol] = (u8)(pk & 0xff);
          } else {
            outf[grow * DD + gcol] = v;
          }
        }
      }
    }
  }
}

// ---------------- launch ----------------
extern "C" void kernel_launch(void* const* d_in, const int* in_sizes, int n_in,
                              void* d_out, int out_size, void* d_ws, size_t ws_size,
                              hipStream_t stream) {
  const float* x    = (const float*)d_in[0];
  const int*   ei   = (const int*)d_in[1];
  const float* W1l  = (const float*)d_in[2];
  const float* b1   = (const float*)d_in[3];
  const float* W1r  = (const float*)d_in[4];
  const float* W2l  = (const float*)d_in[5];
  const float* b2   = (const float*)d_in[6];
  const float* W2r  = (const float*)d_in[7];
  float* out = (float*)d_out;

  const int* srcIdx = ei;        // edge_index[0]
  const int* tgtIdx = ei + NE;   // edge_index[1]

  char* ws = (char*)d_ws;
  // workspace layout (bytes)
  int* cnt    = (int*)(ws + 0);                       // 3,200,000
  int* col    = (int*)(ws + 3200000);                 // 12,800,000
  u16* x_bf   = (u16*)(ws + 16000000);                // 25,600,000
  u16* h_bf   = (u16*)(ws + 41600000);                // 25,600,000
  u8*  x_f8   = (u8*) (ws + 67200000);                // 12,800,000
  u8*  h_f8   = (u8*) (ws + 80000000);                // 12,800,000
  u16* Wc1T   = (u16*)(ws + 92800000);                // 262,144
  u16* Wc2T   = (u16*)(ws + 93062144);                // 262,144
  // total ~93.3 MB

  hipMemsetAsync(cnt, 0, NN * CSTR * sizeof(int), stream);
  k_prep<<<PREP_GRID, 256, 0, stream>>>(srcIdx, tgtIdx, cnt, col, x, x_bf,
                                        (u32*)x_f8,
                                        W1l, W1r, W2l, W2r, Wc1T, Wc2T);

  const int ggrid = (NN + BM - 1) / BM;  // 782

  // layer 1 (fused gather+GEMM)
  k_layer<1><<<ggrid, 256, 0, stream>>>(x_f8, cnt, col, x_bf, Wc1T, b1,
                                        h_bf, h_f8, nullptr, NN);
  // layer 2 (fused gather+GEMM)
  k_layer<2><<<ggrid, 256, 0, stream>>>(h_f8, cnt, col, h_bf, Wc2T, b2,
                                        nullptr, nullptr, out, NN);
}

// Round 16
// 188.701 us; speedup vs baseline: 1.9038x; 1.9038x over previous
//
#include <hip/hip_runtime.h>
#include <hip/hip_bf16.h>

#define NN 50000
#define NE 800000
#define DD 256
#define KK 512    // concat K for fused GEMM
#define PAD 64    // padded CSR row stride (max deg ~45 at 8 sigma; P(>64) ~ 0)
#define CSTR 4    // counter stride in ints (16 B apart; R8 showed chain structure not the bottleneck)

// prep roles: blocks 0..6249 alternate fill/conv (1:1); then conv rest; then wcT.
#define FB 3125
#define CB 12500
#define WB 1024
#define PREP_GRID (2 * FB + (CB - FB) + WB)   // 16649

typedef unsigned short u16;
typedef unsigned int   u32;
typedef unsigned char  u8;
typedef __attribute__((ext_vector_type(8))) __bf16 bf16x8;
typedef __attribute__((ext_vector_type(4))) float  f32x4;
typedef __attribute__((ext_vector_type(2))) float  f32x2;
typedef __attribute__((ext_vector_type(8))) u16    u16x8;
typedef __attribute__((ext_vector_type(4))) u16    u16x4;

#define GLOAD_LDS16(g, l) \
  __builtin_amdgcn_global_load_lds((const __attribute__((address_space(1))) void*)(g), \
                                   (__attribute__((address_space(3))) void*)(l), 16, 0, 0)

static __device__ __forceinline__ u16 f2bf(float f) {
  u32 u = __float_as_uint(f);
  u32 r = (u + 0x7FFFu + ((u >> 16) & 1u)) >> 16;
  return (u16)r;
}

// ---------------- fused prep: INTERLEAVED CSR fill + f32->{bf16,fp8} + WcT ------
__global__ void k_prep(const int* __restrict__ src, const int* __restrict__ tgt,
                       int* __restrict__ cnt, int* __restrict__ col,
                       const float* __restrict__ x, u16* __restrict__ x_bf,
                       u32* __restrict__ x_f8,
                       const float* __restrict__ W1l, const float* __restrict__ W1r,
                       const float* __restrict__ W2l, const float* __restrict__ W2r,
                       u16* __restrict__ Wc1T, u16* __restrict__ Wc2T) {
  const int b = blockIdx.x;
  int role, idx;
  if (b < 2 * FB) {            // alternate fill / conv -> co-resident from dispatch 0
    role = b & 1;              // 0 = fill, 1 = conv
    idx = b >> 1;
  } else if (b < 2 * FB + (CB - FB)) {
    role = 1;                  // conv remainder
    idx = FB + (b - 2 * FB);
  } else {
    role = 2;                  // wcT
    idx = b - (2 * FB + (CB - FB));
  }

  if (role == 0) {
    // CSR fill (histogram-as-cursor, padded rows)
    int i = idx * 256 + threadIdx.x;
    int t = tgt[i];
    int p = atomicAdd(&cnt[t * CSTR], 1);
    if (p < PAD) col[t * PAD + p] = src[i];
  } else if (role == 1) {
    // x -> bf16 (GEMM operand) and fp8 e4m3 (gather table), 4 floats/thread
    int i = idx * 256 + threadIdx.x;
    const float4 v = *reinterpret_cast<const float4*>(x + i * 4);
    u16x4 o; o.x = f2bf(v.x); o.y = f2bf(v.y); o.z = f2bf(v.z); o.w = f2bf(v.w);
    *reinterpret_cast<u16x4*>(x_bf + i * 4) = o;
    int pk = __builtin_amdgcn_cvt_pk_fp8_f32(v.x, v.y, 0, false);
    pk = __builtin_amdgcn_cvt_pk_fp8_f32(v.z, v.w, pk, true);
    x_f8[i] = (u32)pk;
  } else {
    // WcT[n][k] (bf16 [256][512]) for both layers, PRE-SWIZZLED chunk ^= n&7
    int gid = idx * 256 + threadIdx.x;  // 262144 total
    int layer = gid >> 17;
    int idx2 = gid & 131071;
    int n = idx2 >> 9, k = idx2 & 511;
    const float* Wl = layer ? W2l : W1l;
    const float* Wr = layer ? W2r : W1r;
    u16* WcT = layer ? Wc2T : Wc1T;
    float v = (k < DD) ? Wl[k * DD + n] : Wr[(k - DD) * DD + n];
    int reg = k >> 6, ko = k & 63;
    int k2 = (reg << 6) + ((((ko >> 3) ^ (n & 7)) << 3)) + (ko & 7);
    WcT[n * KK + k2] = f2bf(v);
  }
}

// ---------------- mean aggregation (padded CSR, fp8 feature table) ----------------
// one wave per node; half-wave (32 lanes) per edge, 8 B (8 fp8 feats)/lane; MLP=4.
__global__ void k_aggregate(const u8* __restrict__ feat8, const int* __restrict__ cnt,
                            const int* __restrict__ col, u16* __restrict__ out) {
  const int wave = threadIdx.x >> 6;
  const int lane = threadIdx.x & 63;
  const int half = lane >> 5;
  const int l32 = lane & 31;
  const int node = blockIdx.x * 4 + wave;
  int deg = cnt[node * CSTR];
  if (deg > PAD) deg = PAD;       // unreachable clamp, keeps mean consistent
  const int s = node * PAD, e = s + deg;
  const int fo = l32 * 8;  // 8 feats per lane (bytes for fp8, u16-elems for out)
  float a[8] = {0.f, 0.f, 0.f, 0.f, 0.f, 0.f, 0.f, 0.f};

#define ACC8(vv)                                                       \
  {                                                                    \
    f32x2 p0 = __builtin_amdgcn_cvt_pk_f32_fp8((int)(vv).x, false);    \
    f32x2 p1 = __builtin_amdgcn_cvt_pk_f32_fp8((int)(vv).x, true);     \
    f32x2 p2 = __builtin_amdgcn_cvt_pk_f32_fp8((int)(vv).y, false);    \
    f32x2 p3 = __builtin_amdgcn_cvt_pk_f32_fp8((int)(vv).y, true);     \
    a[0] += p0.x; a[1] += p0.y; a[2] += p1.x; a[3] += p1.y;            \
    a[4] += p2.x; a[5] += p2.y; a[6] += p3.x; a[7] += p3.y;            \
  }

  int i = s + half;
  // main loop: 4 edges per half-wave per iteration (8 edges/wave/iter)
  for (; i + 6 < e; i += 8) {
    int c0 = col[i], c1 = col[i + 2], c2 = col[i + 4], c3 = col[i + 6];
    uint2 v0 = *reinterpret_cast<const uint2*>(feat8 + c0 * DD + fo);
    uint2 v1 = *reinterpret_cast<const uint2*>(feat8 + c1 * DD + fo);
    uint2 v2 = *reinterpret_cast<const uint2*>(feat8 + c2 * DD + fo);
    uint2 v3 = *reinterpret_cast<const uint2*>(feat8 + c3 * DD + fo);
    ACC8(v0) ACC8(v1) ACC8(v2) ACC8(v3)
  }
  // tail
  for (; i < e; i += 2) {
    uint2 v = *reinterpret_cast<const uint2*>(feat8 + col[i] * DD + fo);
    ACC8(v)
  }
#undef ACC8
  // combine halves: lane l += lane l^32
#pragma unroll
  for (int j = 0; j < 8; ++j) a[j] += __shfl_xor(a[j], 32, 64);

  if (half == 0) {
    const float scale = (deg > 0) ? 1.0f / (float)deg : 0.0f;
    u16x8 o;
#pragma unroll
    for (int j = 0; j < 8; ++j) o[j] = f2bf(a[j] * scale);
    *reinterpret_cast<u16x8*>(out + node * DD + fo) = o;
  }
}

// ---------------- fused GEMM: out = [A0|A1] @ Wc + bias (+relu) ----------------
// BM=64 x BN=256 (full width -> A streamed once; 782-block grid keeps all CUs fed).
// 4 waves, 64x64 each. global_load_lds width=16; swizzle via source address.
// LAYER==1 additionally emits h in fp8 for the layer-2 gather.
#define BM 64
#define BN 256
#define BK 64

template <int LAYER>
__global__ void k_gemm_fused(const u16* __restrict__ A0, const u16* __restrict__ A1,
                             const u16* __restrict__ WcT, const float* __restrict__ bias,
                             u16* __restrict__ outb, u8* __restrict__ outf8,
                             float* __restrict__ outf, int M) {
  __shared__ alignas(16) u16 lA[BM * BK];   // 8 KB
  __shared__ alignas(16) u16 lB[BN * BK];   // 32 KB
  const int tid = threadIdx.x;
  const int rowBase = blockIdx.x * BM;
  const int wave = tid >> 6, lane = tid & 63;
  const int wc = wave;  // 4 waves across N, each 64 cols
  const int l8 = lane >> 3;   // row within 8-row staging group
  const int ch = lane & 7;    // 16 B chunk within 128 B row

  f32x4 acc[4][4] = {};

  for (int k0 = 0; k0 < KK; k0 += BK) {
    if (k0) __syncthreads();
    const u16* Asrc = (k0 < DD) ? A0 : A1;
    const int kk = k0 & (DD - 1);
    // stage A: 64 rows x 128 B; wave stages rows [wave*16, wave*16+16)
#pragma unroll
    for (int j = 0; j < 2; ++j) {
      int row = wave * 16 + j * 8 + l8;
      const u16* g = Asrc + (size_t)(rowBase + row) * DD + kk + ((ch ^ (row & 7)) << 3);
      GLOAD_LDS16(g, &lA[(wave * 16 + j * 8) * BK]);
    }
    // stage B: 256 rows x 128 B; wave stages rows [wave*64, wave*64+64), linear
#pragma unroll
    for (int j = 0; j < 8; ++j) {
      int row = wave * 64 + j * 8 + l8;
      const u16* g = WcT + (size_t)row * KK + k0 + (ch << 3);
      GLOAD_LDS16(g, &lB[(wave * 64 + j * 8) * BK]);
    }
    __syncthreads();  // compiler drains vmcnt before s_barrier

#pragma unroll
    for (int ks = 0; ks < 2; ++ks) {
      const int kbyte = ks * 64 + (lane >> 4) * 16;
      bf16x8 af[4], bfg[4];
#pragma unroll
      for (int m = 0; m < 4; ++m) {
        int row = m * 16 + (lane & 15);
        af[m] = *reinterpret_cast<const bf16x8*>((const char*)lA + row * 128 + (kbyte ^ ((row & 7) << 4)));
      }
#pragma unroll
      for (int n = 0; n < 4; ++n) {
        int row = wc * 64 + n * 16 + (lane & 15);
        bfg[n] = *reinterpret_cast<const bf16x8*>((const char*)lB + row * 128 + (kbyte ^ ((row & 7) << 4)));
      }
#pragma unroll
      for (int m = 0; m < 4; ++m)
#pragma unroll
        for (int n = 0; n < 4; ++n)
          acc[m][n] = __builtin_amdgcn_mfma_f32_16x16x32_bf16(af[m], bfg[n], acc[m][n], 0, 0, 0);
    }
  }

  // epilogue: D layout col = lane&15, row = (lane>>4)*4 + reg  [m89-verified]
  const int lrow = (lane >> 4) * 4;
  const int lcol = lane & 15;
#pragma unroll
  for (int n = 0; n < 4; ++n) {
    const int gcol = wc * 64 + n * 16 + lcol;
    const float bv = bias[gcol];
#pragma unroll
    for (int m = 0; m < 4; ++m) {
#pragma unroll
      for (int r = 0; r < 4; ++r) {
        const int grow = rowBase + m * 16 + lrow + r;
        if (grow < M) {
          float v = acc[m][n][r] + bv;
          if (LAYER == 1) {
            v = fmaxf(v, 0.0f);
            outb[grow * DD + gcol] = f2bf(v);
            int pk = __builtin_amdgcn_cvt_pk_fp8_f32(v, 0.0f, 0, false);
            outf8[grow * DD + gcol] = (u8)(pk & 0xff);
          } else {
            outf[grow * DD + gcol] = v;
          }
        }
      }
    }
  }
}

// ---------------- launch ----------------
extern "C" void kernel_launch(void* const* d_in, const int* in_sizes, int n_in,
                              void* d_out, int out_size, void* d_ws, size_t ws_size,
                              hipStream_t stream) {
  const float* x    = (const float*)d_in[0];
  const int*   ei   = (const int*)d_in[1];
  const float* W1l  = (const float*)d_in[2];
  const float* b1   = (const float*)d_in[3];
  const float* W1r  = (const float*)d_in[4];
  const float* W2l  = (const float*)d_in[5];
  const float* b2   = (const float*)d_in[6];
  const float* W2r  = (const float*)d_in[7];
  float* out = (float*)d_out;

  const int* srcIdx = ei;        // edge_index[0]
  const int* tgtIdx = ei + NE;   // edge_index[1]

  char* ws = (char*)d_ws;
  // workspace layout (bytes)
  int* cnt    = (int*)(ws + 0);                       // 50000*4*4 = 800,000
  int* col    = (int*)(ws + 800000);                  // 12,800,000
  u16* x_bf   = (u16*)(ws + 13600000);                // 25,600,000
  u16* h_bf   = (u16*)(ws + 39200000);                // 25,600,000
  u16* agg_bf = (u16*)(ws + 64800000);                // 25,600,000
  u8*  x_f8   = (u8*) (ws + 90400000);                // 12,800,000
  u8*  h_f8   = (u8*) (ws + 103200000);               // 12,800,000
  u16* Wc1T   = (u16*)(ws + 116000000);               // 262,144
  u16* Wc2T   = (u16*)(ws + 116262144);               // 262,144
  // total ~116.5 MB

  hipMemsetAsync(cnt, 0, NN * CSTR * sizeof(int), stream);
  k_prep<<<PREP_GRID, 256, 0, stream>>>(srcIdx, tgtIdx, cnt, col, x, x_bf,
                                        (u32*)x_f8,
                                        W1l, W1r, W2l, W2r, Wc1T, Wc2T);

  const int ggrid = (NN + BM - 1) / BM;  // 782

  // layer 1
  k_aggregate<<<NN / 4, 256, 0, stream>>>(x_f8, cnt, col, agg_bf);
  k_gemm_fused<1><<<ggrid, 256, 0, stream>>>(agg_bf, x_bf, Wc1T, b1, h_bf, h_f8, nullptr, NN);
  // layer 2
  k_aggregate<<<NN / 4, 256, 0, stream>>>(h_f8, cnt, col, agg_bf);
  k_gemm_fused<2><<<ggrid, 256, 0, stream>>>(agg_bf, h_bf, Wc2T, b2, nullptr, nullptr, out, NN);
}